// Round 1
// 379.680 us; speedup vs baseline: 1.1595x; 1.1595x over previous
//
#include <hip/hip_runtime.h>
#include <math.h>

#define DEV_INLINE __device__ __forceinline__

constexpr int NB = 2048;   // batch
constexpr int C  = 64;     // d_k == d_v channels
constexpr int L  = 128;    // seq len == d_model
constexpr int DT = 32;     // d_trans
constexpr int NH = 16;     // heads
constexpr int KW = 13;
constexpr int PADC = 6;
constexpr float LN_EPS = 1e-3f;
constexpr float RTEMPER = 0.08838834764831845f; // 1/sqrt(128)

using frag_ab = __attribute__((ext_vector_type(8))) short;  // 8 bf16
using frag_cd = __attribute__((ext_vector_type(4))) float;  // 4 fp32

union alignas(16) F16x8 { short s[8]; short4 h[2]; frag_ab f; };

DEV_INLINE short f2bf(float x) {   // fp32 -> bf16 RNE
    unsigned u = __float_as_uint(x);
    unsigned r = (u + 0x7FFFu + ((u >> 16) & 1u)) >> 16;
    return (short)r;
}
DEV_INLINE unsigned pack2bf(float a, float b) {
    return (unsigned)(unsigned short)f2bf(a) | ((unsigned)(unsigned short)f2bf(b) << 16);
}

// ============ K0: pre-pack ALL weights into MFMA-fragment-ordered bf16 =====
// (unchanged from verified kernel)
__global__ __launch_bounds__(256) void k0_prep(
    const float* __restrict__ wqs, const float* __restrict__ wks,
    const float* __restrict__ wvs, const float* __restrict__ pw,
    const float* __restrict__ cqw, const float* __restrict__ ckw,
    const float* __restrict__ cvw, const float* __restrict__ fcw,
    short* __restrict__ wqB, short* __restrict__ wkB, short* __restrict__ wvB,
    short* __restrict__ projB,
    short* __restrict__ cqA, short* __restrict__ ckA, short* __restrict__ cvA,
    short* __restrict__ fcA)
{
    int idx = blockIdx.x * 256 + threadIdx.x;   // 46080 total
    if (idx >= 46080) return;
    F16x8 u;
    if (idx < 32768) {
        int arr = idx >> 13;          // 0..3
        int rem = idx & 8191;         // (h*8 + f)*64 + lane
        int h   = rem >> 9;
        int f   = (rem >> 6) & 7;
        int ln  = rem & 63;
        if (arr < 3) {
            const float* w = (arr == 0) ? wqs : (arr == 1 ? wks : wvs);
            int kt = f >> 1, nt = f & 1;
            int n = nt * 16 + (ln & 15);
            int kb = kt * 32 + ((ln >> 4) << 3);
            #pragma unroll
            for (int j = 0; j < 8; ++j)
                u.s[j] = f2bf(w[h * 4096 + (kb + j) * 32 + n]);
            short* dst = (arr == 0) ? wqB : (arr == 1 ? wkB : wvB);
            *(F16x8*)(dst + rem * 8) = u;
        } else {
            int m = f * 16 + (ln & 15);
            int db = (ln >> 4) << 3;
            #pragma unroll
            for (int j = 0; j < 8; ++j)
                u.s[j] = f2bf(pw[m * 512 + h * 32 + db + j]);
            *(F16x8*)(projB + rem * 8) = u;
        }
    } else {
        int idx2 = idx - 32768;           // 0..13311
        int arr2 = idx2 / 3328;           // 0..3 : cq, ck, cv, fc
        int rem2 = idx2 - arr2 * 3328;    // slot = f*64 + lane
        int f  = rem2 >> 6;               // 0..51
        int ln = rem2 & 63;
        int q8 = (ln >> 4) << 3;
        if (arr2 < 3) {
            const float* w = (arr2 == 0) ? cqw : (arr2 == 1 ? ckw : cvw);
            int mt = f & 1, kt = (f >> 1) & 1, kw = f >> 2;
            int m = mt * 16 + (ln & 15);
            int cib = kt * 32 + q8;
            #pragma unroll
            for (int j = 0; j < 8; ++j)
                u.s[j] = f2bf(w[m * (C * KW) + (cib + j) * KW + kw]);
            short* dst = (arr2 == 0) ? cqA : (arr2 == 1 ? ckA : cvA);
            *(F16x8*)(dst + rem2 * 8) = u;
        } else {
            int mt = f & 3, kw = f >> 2;
            int m = mt * 16 + (ln & 15);
            #pragma unroll
            for (int j = 0; j < 8; ++j)
                u.s[j] = f2bf(fcw[m * (DT * KW) + (q8 + j) * KW + kw]);
            *(F16x8*)(fcA + rem2 * 8) = u;
        }
    }
}

// ---------------- per-wave fragment helpers (stride-36 tiles) --------------
DEV_INLINE frag_ab ld_frag(const short* buf, int rbase, int lane) {
    const short* p = buf + (rbase + (lane & 15)) * 36 + ((lane >> 4) << 3);
    F16x8 u;
    u.h[0] = *(const short4*)p;
    u.h[1] = *(const short4*)(p + 4);
    return u.f;
}
DEV_INLINE void st_cfrag(short* buf, frag_cd c, int mt, int nt, int lane) {
    const int col = nt * 16 + (lane & 15);
    const int r0  = mt * 16 + ((lane >> 4) << 2);
    #pragma unroll
    for (int i = 0; i < 4; ++i) buf[(r0 + i) * 36 + col] = f2bf(c[i]);
}
DEV_INLINE void st_cfragT(short* buf, frag_cd c, int mt, int nt, int lane) {
    const int col = nt * 16 + (lane & 15);
    const int r0  = mt * 16 + ((lane >> 4) << 2);
    #pragma unroll
    for (int i = 0; i < 4; ++i) buf[col * 36 + r0 + i] = f2bf(c[i]);
}

// head projection: A read strided from a [32][136] bf16 tile, B frags from global
DEV_INLINE void proj_head(const short* __restrict__ tile, const short* __restrict__ bF,
                          short* dst, bool transp, int lane) {
    frag_ab B[8];
    #pragma unroll
    for (int i = 0; i < 8; ++i)
        B[i] = *(const frag_ab*)(bF + (i * 64 + lane) * 8);
    #pragma unroll
    for (int mt = 0; mt < 2; ++mt) {
        frag_ab A[4];
        #pragma unroll
        for (int kt = 0; kt < 4; ++kt) {
            const short* p = tile + (mt * 16 + (lane & 15)) * 136 + kt * 32 + ((lane >> 4) << 3);
            F16x8 u; u.h[0] = *(const short4*)p; u.h[1] = *(const short4*)(p + 4);
            A[kt] = u.f;
        }
        #pragma unroll
        for (int nt = 0; nt < 2; ++nt) {
            frag_cd acc = {0.f, 0.f, 0.f, 0.f};
            #pragma unroll
            for (int kt = 0; kt < 4; ++kt)
                acc = __builtin_amdgcn_mfma_f32_16x16x32_bf16(A[kt], B[kt*2+nt], acc, 0, 0, 0);
            if (transp) st_cfragT(dst, acc, mt, nt, lane);
            else        st_cfrag (dst, acc, mt, nt, lane);
        }
    }
}

// ============ fused: conv x3 -> heads+attn+proj -> fconv+residual+LN =======
// LDS map (53760 B total):
//   region A [0, 26112):  3x [32][136] bf16 conv-out tiles (q,k,v)
//                         -> later aliased by xT2 [140][40] bf16 (fconv staging)
//   region B [26112, 53760): conv staging xT [140][72] bf16 (20160 B)
//                         -> later 4x per-wave bufs (3x 32x36 bf16 = 6912 B each)
//   zb [0, 33792): f32 [64][132] (LN input) — written after all above are dead
__global__ __launch_bounds__(256, 3) void k_fused(
    const float* __restrict__ qx, const float* __restrict__ kx, const float* __restrict__ vx,
    const short* __restrict__ cqA, const short* __restrict__ ckA, const short* __restrict__ cvA,
    const float* __restrict__ cqb, const float* __restrict__ ckb, const float* __restrict__ cvb,
    const short* __restrict__ wqB, const short* __restrict__ wkB, const short* __restrict__ wvB,
    const short* __restrict__ projB, const float* __restrict__ proj_b,
    const short* __restrict__ fA, const float* __restrict__ fcb,
    const float* __restrict__ ln_a, const float* __restrict__ ln_b,
    float* __restrict__ out)
{
    __shared__ __align__(16) char smem[53760];
    short* tiles = (short*)smem;               // 3 x 4352 shorts
    short* regB  = (short*)(smem + 26112);     // 13824 shorts

    const int b = blockIdx.x, tid = threadIdx.x;
    const int lane = tid & 63, wv = tid >> 6;
    const int qq = lane >> 4, nlo = lane & 15;
    const int nb0 = wv * 32 + nlo;

    // ------------------- stage 1: three conv1d (C=64 -> DT=32) -------------
    {
        const float* xs[3] = { qx + (size_t)b * 8192, kx + (size_t)b * 8192, vx + (size_t)b * 8192 };
        const short* was[3] = { cqA, ckA, cvA };
        const float* bss[3] = { cqb, ckb, cvb };
        short* xT = regB;                      // [140][72] bf16
        #pragma unroll
        for (int inp = 0; inp < 3; ++inp) {
            const float* xb = xs[inp];
            // stage + transpose + bf16 (2 channels per 4B store), float4 loads
            for (int i = tid; i < 1024; i += 256) {
                int cp = i >> 5, l4 = (i & 31) << 2;
                float4 a  = *(const float4*)(xb + (2 * cp) * 128 + l4);
                float4 c2 = *(const float4*)(xb + (2 * cp + 1) * 128 + l4);
                *(unsigned*)&xT[(l4 + 6) * 72 + 2 * cp] = pack2bf(a.x, c2.x);
                *(unsigned*)&xT[(l4 + 7) * 72 + 2 * cp] = pack2bf(a.y, c2.y);
                *(unsigned*)&xT[(l4 + 8) * 72 + 2 * cp] = pack2bf(a.z, c2.z);
                *(unsigned*)&xT[(l4 + 9) * 72 + 2 * cp] = pack2bf(a.w, c2.w);
            }
            for (int i = tid; i < 384; i += 256) {   // zero halo rows, cols 0..63
                int rr = i >> 5, c2i = (i & 31) * 2;
                int r = rr < 6 ? rr : 128 + rr;
                *(unsigned*)&xT[r * 72 + c2i] = 0u;
            }

            frag_cd acc[2][2];
            const float* bias = bss[inp];
            #pragma unroll
            for (int mt = 0; mt < 2; ++mt)
                #pragma unroll
                for (int i = 0; i < 4; ++i) {
                    float bv = bias[mt * 16 + qq * 4 + i];
                    acc[mt][0][i] = bv; acc[mt][1][i] = bv;
                }
            __syncthreads();

            const short* wA = was[inp];
            for (int f = 0; f < 26; ++f) {     // f = kw*2 + kt
                const int kw = f >> 1;
                frag_ab a0 = *(const frag_ab*)(wA + ((f * 2 + 0) * 64 + lane) * 8);
                frag_ab a1 = *(const frag_ab*)(wA + ((f * 2 + 1) * 64 + lane) * 8);
                const short* bp = &xT[(nb0 + kw) * 72 + (f & 1) * 32 + qq * 8];
                frag_ab b0 = *(const frag_ab*)bp;
                frag_ab b1 = *(const frag_ab*)(bp + 16 * 72);
                acc[0][0] = __builtin_amdgcn_mfma_f32_16x16x32_bf16(a0, b0, acc[0][0], 0, 0, 0);
                acc[0][1] = __builtin_amdgcn_mfma_f32_16x16x32_bf16(a0, b1, acc[0][1], 0, 0, 0);
                acc[1][0] = __builtin_amdgcn_mfma_f32_16x16x32_bf16(a1, b0, acc[1][0], 0, 0, 0);
                acc[1][1] = __builtin_amdgcn_mfma_f32_16x16x32_bf16(a1, b1, acc[1][1], 0, 0, 0);
            }

            // C tile straight into region A (rows = DT channel t, cols = l)
            short* dstTile = tiles + inp * 4352;
            #pragma unroll
            for (int mt = 0; mt < 2; ++mt)
                #pragma unroll
                for (int ntl = 0; ntl < 2; ++ntl) {
                    int col = wv * 32 + ntl * 16 + nlo;
                    int r0  = mt * 16 + qq * 4;
                    #pragma unroll
                    for (int i = 0; i < 4; ++i)
                        dstTile[(r0 + i) * 136 + col] = f2bf(acc[mt][ntl][i]);
                }
            __syncthreads();   // xT reads done; next inp may overwrite; tiles visible
        }
    }

    // ------------------- stage 2: heads + attention + out-proj -------------
    short* buf0 = regB + wv * 3456;
    short* buf1 = buf0 + 1152;
    short* buf2 = buf1 + 1152;

    frag_cd oc[2][2];    // per-wave proj slice: rows t (32), cols l = wv*32..wv*32+31
    #pragma unroll
    for (int mt = 0; mt < 2; ++mt)
        #pragma unroll
        for (int nt = 0; nt < 2; ++nt)
            oc[mt][nt] = frag_cd{0.f, 0.f, 0.f, 0.f};

    for (int r = 0; r < 4; ++r) {
        const int h = r * 4 + wv;
        proj_head(tiles,        wqB + h * 4096, buf0, false, lane);
        proj_head(tiles + 4352, wkB + h * 4096, buf1, false, lane);
        proj_head(tiles + 8704, wvB + h * 4096, buf2, true,  lane);

        frag_ab bk0 = ld_frag(buf1, 0, lane), bk1 = ld_frag(buf1, 16, lane);
        frag_cd S[2][2];
        #pragma unroll
        for (int mt = 0; mt < 2; ++mt) {
            frag_ab aq = ld_frag(buf0, mt * 16, lane);
            frag_cd z = {0.f, 0.f, 0.f, 0.f};
            S[mt][0] = __builtin_amdgcn_mfma_f32_16x16x32_bf16(aq, bk0, z, 0, 0, 0);
            S[mt][1] = __builtin_amdgcn_mfma_f32_16x16x32_bf16(aq, bk1, z, 0, 0, 0);
        }

        #pragma unroll
        for (int mt = 0; mt < 2; ++mt) {
            #pragma unroll
            for (int i = 0; i < 4; ++i) {
                float s0 = S[mt][0][i] * RTEMPER;
                float s1 = S[mt][1][i] * RTEMPER;
                float mx = fmaxf(s0, s1);
                #pragma unroll
                for (int off = 1; off < 16; off <<= 1)
                    mx = fmaxf(mx, __shfl_xor(mx, off, 64));
                float e0 = __expf(s0 - mx), e1 = __expf(s1 - mx);
                float sm = e0 + e1;
                #pragma unroll
                for (int off = 1; off < 16; off <<= 1)
                    sm += __shfl_xor(sm, off, 64);
                const float inv = 1.f / sm;
                const int row = mt * 16 + ((lane >> 4) << 2) + i;
                buf0[row * 36 + (lane & 15)]      = f2bf(e0 * inv);
                buf0[row * 36 + 16 + (lane & 15)] = f2bf(e1 * inv);
            }
        }

        frag_ab bv0 = ld_frag(buf2, 0, lane), bv1 = ld_frag(buf2, 16, lane);
        #pragma unroll
        for (int mt = 0; mt < 2; ++mt) {
            frag_ab ap = ld_frag(buf0, mt * 16, lane);
            frag_cd z = {0.f, 0.f, 0.f, 0.f};
            frag_cd O0 = __builtin_amdgcn_mfma_f32_16x16x32_bf16(ap, bv0, z, 0, 0, 0);
            frag_cd O1 = __builtin_amdgcn_mfma_f32_16x16x32_bf16(ap, bv1, z, 0, 0, 0);
            st_cfrag(buf1, O0, mt, 0, lane);
            st_cfrag(buf1, O1, mt, 1, lane);
        }
        __syncthreads();   // all 4 waves' O tiles ready

        // out-proj: each wave accumulates its own 32-col slice over this round's 4 heads
        #pragma unroll
        for (int hh = 0; hh < 4; ++hh) {
            const short* ob = regB + hh * 3456 + 1152;     // wave hh's buf1 (O tile)
            frag_ab ao0 = ld_frag(ob, 0, lane), ao1 = ld_frag(ob, 16, lane);
            const int hq = r * 4 + hh;
            #pragma unroll
            for (int nt = 0; nt < 2; ++nt) {
                frag_ab pb = *(const frag_ab*)(projB + hq * 4096 + ((wv * 2 + nt) * 64 + lane) * 8);
                oc[0][nt] = __builtin_amdgcn_mfma_f32_16x16x32_bf16(ao0, pb, oc[0][nt], 0, 0, 0);
                oc[1][nt] = __builtin_amdgcn_mfma_f32_16x16x32_bf16(ao1, pb, oc[1][nt], 0, 0, 0);
            }
        }
        __syncthreads();   // proj reads done before next round overwrites bufs
    }

    // ------------------- stage 3: fconv staging from registers -------------
    short* xT2 = tiles;   // [140][40] bf16, aliases dead qkv tiles
    for (int i = tid; i < 384; i += 256) {   // zero halo rows, cols 0..31
        int rr = i >> 5, cc = i & 31;
        int rw = rr < 6 ? rr : 128 + rr;
        xT2[rw * 40 + cc] = 0;
    }
    {
        const float pbv0 = proj_b[wv * 32 + (lane & 15)];
        const float pbv1 = proj_b[wv * 32 + 16 + (lane & 15)];
        #pragma unroll
        for (int mt = 0; mt < 2; ++mt)
            #pragma unroll
            for (int nt = 0; nt < 2; ++nt) {
                const int l = wv * 32 + nt * 16 + (lane & 15);
                const float pbv = nt ? pbv1 : pbv0;
                #pragma unroll
                for (int i = 0; i < 4; ++i) {
                    const int t = mt * 16 + ((lane >> 4) << 2) + i;
                    xT2[(l + 6) * 40 + t] = f2bf(oc[mt][nt][i] + pbv);
                }
            }
    }
    __syncthreads();

    // ------------------- stage 4: final conv (DT->C) ------------------------
    frag_cd fa[4][2];
    #pragma unroll
    for (int mt = 0; mt < 4; ++mt)
        #pragma unroll
        for (int i = 0; i < 4; ++i) {
            float bv = fcb[mt * 16 + qq * 4 + i];
            fa[mt][0][i] = bv; fa[mt][1][i] = bv;
        }
    for (int kw = 0; kw < 13; ++kw) {
        frag_ab a[4];
        #pragma unroll
        for (int mt = 0; mt < 4; ++mt)
            a[mt] = *(const frag_ab*)(fA + ((kw * 4 + mt) * 64 + lane) * 8);
        const short* bp = &xT2[(nb0 + kw) * 40 + qq * 8];
        frag_ab b0 = *(const frag_ab*)bp;
        frag_ab b1 = *(const frag_ab*)(bp + 16 * 40);
        #pragma unroll
        for (int mt = 0; mt < 4; ++mt) {
            fa[mt][0] = __builtin_amdgcn_mfma_f32_16x16x32_bf16(a[mt], b0, fa[mt][0], 0, 0, 0);
            fa[mt][1] = __builtin_amdgcn_mfma_f32_16x16x32_bf16(a[mt], b1, fa[mt][1], 0, 0, 0);
        }
    }
    __syncthreads();   // xT2 reads complete before zb overwrites

    float* zb = (float*)smem;   // [64][132] f32
    #pragma unroll
    for (int mt = 0; mt < 4; ++mt)
        #pragma unroll
        for (int ntl = 0; ntl < 2; ++ntl) {
            int col = wv * 32 + ntl * 16 + nlo;
            int r0  = mt * 16 + qq * 4;
            #pragma unroll
            for (int i = 0; i < 4; ++i)
                zb[(r0 + i) * 132 + col] = fa[mt][ntl][i];
        }
    __syncthreads();

    // ------------------- stage 5: residual + LayerNorm ----------------------
    const int cq2 = tid >> 4, lq = tid & 15, l0 = lq * 8;
    const float4* la4 = (const float4*)(ln_a + l0);
    const float4* lb4 = (const float4*)(ln_b + l0);
    float4 A0 = la4[0], A1 = la4[1], B0 = lb4[0], B1 = lb4[1];
    for (int g = 0; g < 4; ++g) {
        const int co = g * 16 + cq2;
        const float4* zr4 = (const float4*)(&zb[co * 132 + l0]);
        float4 z0 = zr4[0], z1 = zr4[1];
        const float4* rr4 = (const float4*)(qx + (size_t)b * (C * L) + co * 128 + l0);
        float4 r0 = rr4[0], r1 = rr4[1];
        float zz[8] = {z0.x + r0.x, z0.y + r0.y, z0.z + r0.z, z0.w + r0.w,
                       z1.x + r1.x, z1.y + r1.y, z1.z + r1.z, z1.w + r1.w};
        float s = 0.f;
        #pragma unroll
        for (int j = 0; j < 8; ++j) s += zz[j];
        #pragma unroll
        for (int off = 1; off < 16; off <<= 1) s += __shfl_xor(s, off, 64);
        const float mu = s * (1.f / 128.f);
        float d[8], ss = 0.f;
        #pragma unroll
        for (int j = 0; j < 8; ++j) { d[j] = zz[j] - mu; ss += d[j] * d[j]; }
        #pragma unroll
        for (int off = 1; off < 16; off <<= 1) ss += __shfl_xor(ss, off, 64);
        const float sigma = sqrtf(ss * (1.f / 127.f));
        const float inv = 1.f / (sigma + LN_EPS);
        float4 o0, o1;
        o0.x = fmaf(d[0] * inv, A0.x, B0.x);
        o0.y = fmaf(d[1] * inv, A0.y, B0.y);
        o0.z = fmaf(d[2] * inv, A0.z, B0.z);
        o0.w = fmaf(d[3] * inv, A0.w, B0.w);
        o1.x = fmaf(d[4] * inv, A1.x, B1.x);
        o1.y = fmaf(d[5] * inv, A1.y, B1.y);
        o1.z = fmaf(d[6] * inv, A1.z, B1.z);
        o1.w = fmaf(d[7] * inv, A1.w, B1.w);
        float4* ow = (float4*)(out + (size_t)b * (C * L) + co * 128 + l0);
        ow[0] = o0; ow[1] = o1;
    }
}

extern "C" void kernel_launch(void* const* d_in, const int* in_sizes, int n_in,
                              void* d_out, int out_size, void* d_ws, size_t ws_size,
                              hipStream_t stream) {
    const float* q    = (const float*)d_in[0];
    const float* k    = (const float*)d_in[1];
    const float* v    = (const float*)d_in[2];
    const float* cq_w = (const float*)d_in[3];  const float* cq_b = (const float*)d_in[4];
    const float* ck_w = (const float*)d_in[5];  const float* ck_b = (const float*)d_in[6];
    const float* cv_w = (const float*)d_in[7];  const float* cv_b = (const float*)d_in[8];
    const float* w_qs = (const float*)d_in[9];
    const float* w_ks = (const float*)d_in[10];
    const float* w_vs = (const float*)d_in[11];
    const float* proj_w = (const float*)d_in[12];
    const float* proj_b = (const float*)d_in[13];
    const float* fc_w = (const float*)d_in[14]; const float* fc_b = (const float*)d_in[15];
    const float* ln_a = (const float*)d_in[16]; const float* ln_b = (const float*)d_in[17];
    float* out = (float*)d_out;

    short* ws16 = (short*)d_ws;
    short* wqB = ws16;
    short* wkB = wqB + 65536;
    short* wvB = wkB + 65536;
    short* projB = wvB + 65536;
    short* cqA = projB + 65536;
    short* ckA = cqA + 26624;
    short* cvA = ckA + 26624;
    short* fcA = cvA + 26624;

    k0_prep<<<180, 256, 0, stream>>>(w_qs, w_ks, w_vs, proj_w,
                                     cq_w, ck_w, cv_w, fc_w,
                                     wqB, wkB, wvB, projB, cqA, ckA, cvA, fcA);
    k_fused<<<NB, 256, 0, stream>>>(q, k, v, cqA, ckA, cvA, cq_b, ck_b, cv_b,
                                    wqB, wkB, wvB, projB, proj_b,
                                    fcA, fc_b, ln_a, ln_b, out);
}